// Round 5
// baseline (182.178 us; speedup 1.0000x reference)
//
#include <hip/hip_runtime.h>
#include <stdint.h>

#define NROWS 16384
#define DIM 512
#define CSPLIT 8
#define COLS_PER_SPLIT (NROWS / CSPLIT)   // 2048
#define BM 512                            // rows per block (8 waves x 64)
#define NT 64                             // cols per tile
#define BK 128                            // k per K-step
#define NTILES (COLS_PER_SPLIT / NT)      // 32
#define PPT (DIM / BK)                    // 4 K-steps per tile
#define NPHASE (NTILES * PPT)             // 128

using i32x4 = __attribute__((ext_vector_type(4))) int;
using char8 = __attribute__((ext_vector_type(8))) signed char;

#define AS1 __attribute__((address_space(1)))
#define AS3 __attribute__((address_space(3)))

// ---------------- Kernel A: L2-normalize + per-row i8 quantize --------------
__global__ __launch_bounds__(256) void knorm(const float* __restrict__ in,
                                             signed char* __restrict__ xq,
                                             float* __restrict__ inv,
                                             float* __restrict__ scl) {
  const int lane = threadIdx.x & 63;
  const int wave = threadIdx.x >> 6;
  const int row = blockIdx.x * 4 + wave;
  const float4* p = (const float4*)(in + (size_t)row * DIM + lane * 8);
  const float4 a = p[0], b = p[1];
  float ss = a.x*a.x + a.y*a.y + a.z*a.z + a.w*a.w
           + b.x*b.x + b.y*b.y + b.z*b.z + b.w*b.w;
  float am = fmaxf(fmaxf(fmaxf(fabsf(a.x), fabsf(a.y)), fmaxf(fabsf(a.z), fabsf(a.w))),
                   fmaxf(fmaxf(fabsf(b.x), fabsf(b.y)), fmaxf(fabsf(b.z), fabsf(b.w))));
  #pragma unroll
  for (int m = 32; m >= 1; m >>= 1) {
    ss += __shfl_xor(ss, m, 64);
    am = fmaxf(am, __shfl_xor(am, m, 64));
  }
  const float iv = 1.0f / fmaxf(sqrtf(ss), 1e-8f);
  const float r127 = 127.0f / am;
  char8 q;
  q[0] = (signed char)(int)rintf(a.x * r127);
  q[1] = (signed char)(int)rintf(a.y * r127);
  q[2] = (signed char)(int)rintf(a.z * r127);
  q[3] = (signed char)(int)rintf(a.w * r127);
  q[4] = (signed char)(int)rintf(b.x * r127);
  q[5] = (signed char)(int)rintf(b.y * r127);
  q[6] = (signed char)(int)rintf(b.z * r127);
  q[7] = (signed char)(int)rintf(b.w * r127);
  *(char8*)(xq + (size_t)row * DIM + lane * 8) = q;
  if (lane == 0) {
    inv[row] = iv;
    scl[row] = am * iv * (1.0f / 127.0f);
  }
}

// ---------------- Kernel B: i8 Gram + fused running argmax (packed keys) ----
// 512 threads = 8 waves (2 per SIMD, barrier-antiphase a la m201); 64 rows per
// wave, A register-resident (128 VGPR). B tiles (64c x 128k = 8 KB) in 4 LDS
// buffers, depth-3 prefetch (1 global_load_lds per thread per K-step),
// counted vmcnt(2). K-step = 4 sub-phases {2 ds_read + stage(q==0) -> barrier
// -> lgkmcnt(0) -> sched_barrier -> setprio(1) 8 MFMA setprio(0) -> barrier}.
// Argmax tracked as packed u32 key: high 21 bits of float(idot*scl[col]+4096),
// low 11 bits = 2047-colInSplit (larger key = bigger dot, ties -> smaller col).
__global__ __launch_bounds__(512, 2) void kdots(const signed char* __restrict__ xq,
                                                const float* __restrict__ scl,
                                                uint32_t* __restrict__ keys) {
  const int tid  = threadIdx.x;
  const int lane = tid & 63;
  const int wave = tid >> 6;
  const int bx = blockIdx.x;
  const int cs = bx & (CSPLIT - 1);     // same-cs blocks land on same XCD (%8)
  const int rb = bx >> 3;
  const int rowbase  = rb * BM + wave * 64;
  const int colsplit = cs * COLS_PER_SPLIT;
  // the one tile (per wave) containing diagonal elements, or -1
  const int tdiag = ((rowbase >> 11) == cs) ? ((rowbase - colsplit) >> 6) : -1;

  __shared__ signed char lds[4][NT * BK];   // 4 x 8 KB
  __shared__ float sscl[COLS_PER_SPLIT];    // 8 KB

  // stage this slice's column scales into LDS (read in epilogue only)
  ((float4*)sscl)[tid] = ((const float4*)(scl + colsplit))[tid];

  // ---- A fragments in registers: 4 rowfrags x 8 kfrags(K=64) = 128 VGPR ----
  i32x4 areg[4][8];
  #pragma unroll
  for (int rf = 0; rf < 4; ++rf) {
    const signed char* ap =
        xq + (size_t)(rowbase + rf * 16 + (lane & 15)) * DIM + ((lane >> 4) * 16);
    #pragma unroll
    for (int kf = 0; kf < 8; ++kf)
      areg[rf][kf] = *(const i32x4*)(ap + kf * 64);
  }

  uint32_t rkey[4][4];
  #pragma unroll
  for (int rf = 0; rf < 4; ++rf)
    #pragma unroll
    for (int r = 0; r < 4; ++r) rkey[rf][r] = 0u;

  // stage one full 8 KB buffer: 1 global_load_lds(16B) per thread
  auto STAGE = [&](int buf, int p) {
    const int tt = p >> 2, kb2 = p & 3;
    const int u = tid;                                   // 0..511
    const int col = colsplit + tt * NT + ((u >> 7) << 4) + (u & 15);
    const int koff = kb2 * BK + ((u >> 4) & 7) * 16;
    const signed char* g = xq + (size_t)col * DIM + koff;
    char* l = ((char*)&lds[buf][0]) + u * 16;
    __builtin_amdgcn_global_load_lds((AS1 const void*)g, (AS3 void*)l, 16, 0, 0);
  };

  __syncthreads();   // sscl visible; drains all prior vmem (vmcnt -> 0)
  STAGE(0, 0); STAGE(1, 1); STAGE(2, 2);   // depth-3 prologue: 3 outstanding

  for (int t = 0; t < NTILES; ++t) {
    i32x4 acc[4][4];
    #pragma unroll
    for (int rf = 0; rf < 4; ++rf)
      #pragma unroll
      for (int cf = 0; cf < 4; ++cf) acc[rf][cf] = (i32x4){0, 0, 0, 0};

    #pragma unroll
    for (int kb = 0; kb < PPT; ++kb) {
      // buffer for this K-step = (t*4+kb)&3 = kb&3 (compile-time per kb)
      asm volatile("s_waitcnt vmcnt(2)" ::: "memory"); // this buf's load done
      __builtin_amdgcn_s_barrier();                    // ...in ALL waves
      asm volatile("" ::: "memory");
      const char* base = (const char*)&lds[kb & 3][0];
      const int pn = (t * PPT + kb + 3) & (NPHASE - 1); // depth-3 prefetch
      #pragma unroll
      for (int q = 0; q < 4; ++q) {                    // sub-phase = one cf
        const i32x4 bf0 = *(const i32x4*)(base + q * 2048 + lane * 16);
        const i32x4 bf1 = *(const i32x4*)(base + q * 2048 + 1024 + lane * 16);
        if (q == 0) STAGE((kb + 3) & 3, pn);
        __builtin_amdgcn_s_barrier();
        asm volatile("s_waitcnt lgkmcnt(0)" ::: "memory");
        __builtin_amdgcn_sched_barrier(0);
        __builtin_amdgcn_s_setprio(1);
        #pragma unroll
        for (int rf = 0; rf < 4; ++rf)
          acc[rf][q] = __builtin_amdgcn_mfma_i32_16x16x64_i8(
              areg[rf][kb * 2 + 0], bf0, acc[rf][q], 0, 0, 0);
        #pragma unroll
        for (int rf = 0; rf < 4; ++rf)
          acc[rf][q] = __builtin_amdgcn_mfma_i32_16x16x64_i8(
              areg[rf][kb * 2 + 1], bf1, acc[rf][q], 0, 0, 0);
        __builtin_amdgcn_s_setprio(0);
        if (q != 3) __builtin_amdgcn_s_barrier();      // q==3: next K-step's
        asm volatile("" ::: "memory");                 // leading barrier covers
      }
    }

    // ---- fused argmax over this 64-col tile: packed-key running max --------
    const int colb0 = t * NT;
    if (t == tdiag) {
      #pragma unroll
      for (int cf = 0; cf < 4; ++cf) {
        const float sc = sscl[colb0 + cf * 16 + (lane & 15)];
        const uint32_t code = 2047u - (uint32_t)(colb0 + cf * 16 + (lane & 15));
        const int gcol = colsplit + colb0 + cf * 16 + (lane & 15);
        #pragma unroll
        for (int rf = 0; rf < 4; ++rf) {
          #pragma unroll
          for (int r = 0; r < 4; ++r) {
            const int grow = rowbase + rf * 16 + (lane >> 4) * 4 + r;
            const float dv = fmaf((float)acc[rf][cf][r], sc, 4096.0f);
            uint32_t key = (__float_as_uint(dv) & 0xFFFFF800u) | code;
            if (gcol == grow) key = 0u;               // mask diagonal
            rkey[rf][r] = rkey[rf][r] > key ? rkey[rf][r] : key;
          }
        }
      }
    } else {
      #pragma unroll
      for (int cf = 0; cf < 4; ++cf) {
        const float sc = sscl[colb0 + cf * 16 + (lane & 15)];
        const uint32_t code = 2047u - (uint32_t)(colb0 + cf * 16 + (lane & 15));
        #pragma unroll
        for (int rf = 0; rf < 4; ++rf) {
          #pragma unroll
          for (int r = 0; r < 4; ++r) {
            const float dv = fmaf((float)acc[rf][cf][r], sc, 4096.0f);
            const uint32_t key = (__float_as_uint(dv) & 0xFFFFF800u) | code;
            rkey[rf][r] = rkey[rf][r] > key ? rkey[rf][r] : key;
          }
        }
      }
    }
  }

  // ---- cross-lane key max within each 16-lane group ------------------------
  #pragma unroll
  for (int m = 1; m <= 8; m <<= 1) {
    #pragma unroll
    for (int rf = 0; rf < 4; ++rf) {
      #pragma unroll
      for (int r = 0; r < 4; ++r) {
        const uint32_t ok =
            (uint32_t)__shfl_xor((int)rkey[rf][r], m, 64);
        rkey[rf][r] = rkey[rf][r] > ok ? rkey[rf][r] : ok;
      }
    }
  }
  if ((lane & 15) == 0) {
    #pragma unroll
    for (int rf = 0; rf < 4; ++rf) {
      #pragma unroll
      for (int r = 0; r < 4; ++r) {
        const int grow = rowbase + rf * 16 + (lane >> 4) * 4 + r;
        keys[cs * NROWS + grow] = rkey[rf][r];
      }
    }
  }
}

// ---------------- Kernel C1: combine splits, exact f32 distance + log -------
__global__ __launch_bounds__(256) void kdist(const float* __restrict__ in,
                                             const float* __restrict__ inv,
                                             const uint32_t* __restrict__ keys,
                                             float* __restrict__ partial) {
  __shared__ float acc4[4];
  const int lane = threadIdx.x & 63;
  const int wave = threadIdx.x >> 6;
  const int row = blockIdx.x * 4 + wave;
  uint32_t bk = 0u; int bs = 0;
  #pragma unroll
  for (int s = 0; s < CSPLIT; ++s) {
    const uint32_t k = keys[s * NROWS + row];
    if (k > bk) { bk = k; bs = s; }
  }
  const int bi = bs * COLS_PER_SPLIT + 2047 - (int)(bk & 2047u);
  const float ii = inv[row], jj = inv[bi];
  const float4* pi = (const float4*)(in + (size_t)row * DIM + lane * 8);
  const float4* pj = (const float4*)(in + (size_t)bi * DIM + lane * 8);
  const float4 a0 = pi[0], a1 = pi[1], b0 = pj[0], b1 = pj[1];
  float d, ss = 0.0f;
  d = a0.x*ii - b0.x*jj + 1e-8f; ss += d*d;
  d = a0.y*ii - b0.y*jj + 1e-8f; ss += d*d;
  d = a0.z*ii - b0.z*jj + 1e-8f; ss += d*d;
  d = a0.w*ii - b0.w*jj + 1e-8f; ss += d*d;
  d = a1.x*ii - b1.x*jj + 1e-8f; ss += d*d;
  d = a1.y*ii - b1.y*jj + 1e-8f; ss += d*d;
  d = a1.z*ii - b1.z*jj + 1e-8f; ss += d*d;
  d = a1.w*ii - b1.w*jj + 1e-8f; ss += d*d;
  #pragma unroll
  for (int m = 32; m >= 1; m >>= 1) ss += __shfl_xor(ss, m, 64);
  if (lane == 0) acc4[wave] = logf(sqrtf(ss) + 1e-8f);
  __syncthreads();
  if (threadIdx.x == 0)
    partial[blockIdx.x] = acc4[0] + acc4[1] + acc4[2] + acc4[3];
}

// ---------------- Kernel C2: final reduce -> loss ---------------------------
__global__ __launch_bounds__(256) void kfinal(const float* __restrict__ partial,
                                              float* __restrict__ out) {
  __shared__ float acc4[4];
  const int lane = threadIdx.x & 63;
  const int wave = threadIdx.x >> 6;
  float s = 0.0f;
  for (int i = threadIdx.x; i < NROWS / 4; i += 256) s += partial[i];
  #pragma unroll
  for (int m = 32; m >= 1; m >>= 1) s += __shfl_xor(s, m, 64);
  if (lane == 0) acc4[wave] = s;
  __syncthreads();
  if (threadIdx.x == 0)
    out[0] = -(acc4[0] + acc4[1] + acc4[2] + acc4[3]) * (1.0f / (float)NROWS);
}

extern "C" void kernel_launch(void* const* d_in, const int* in_sizes, int n_in,
                              void* d_out, int out_size, void* d_ws, size_t ws_size,
                              hipStream_t stream) {
  const float* in = (const float*)d_in[0];
  char* ws = (char*)d_ws;
  signed char* xq   = (signed char*)(ws);                  //  8,388,608 B
  float*       inv  = (float*)(ws + 8388608);              //     65,536 B
  float*       scl  = (float*)(ws + 8454144);              //     65,536 B
  uint32_t*    keys = (uint32_t*)(ws + 8519680);           //    524,288 B
  float*       part = (float*)(ws + 9043968);              //     16,384 B

  knorm<<<NROWS / 4, 256, 0, stream>>>(in, xq, inv, scl);
  kdots<<<(NROWS / BM) * CSPLIT, 512, 0, stream>>>(xq, scl, keys);
  kdist<<<NROWS / 4, 256, 0, stream>>>(in, inv, keys, part);
  kfinal<<<1, 256, 0, stream>>>(part, (float*)d_out);
}

// Round 6
// 164.456 us; speedup vs baseline: 1.1078x; 1.1078x over previous
//
#include <hip/hip_runtime.h>
#include <stdint.h>

#define NROWS 16384
#define DIM 512
#define CSPLIT 8
#define COLS_PER_SPLIT (NROWS / CSPLIT)   // 2048
#define BM 256                            // rows per block (4 waves x 64)
#define NT 64                             // cols per tile
#define BK 128                            // k per K-step
#define NTILES (COLS_PER_SPLIT / NT)      // 32
#define PPT (DIM / BK)                    // 4 K-steps per tile
#define NPHASE (NTILES * PPT)             // 128

using i32x4 = __attribute__((ext_vector_type(4))) int;
using char8 = __attribute__((ext_vector_type(8))) signed char;

#define AS1 __attribute__((address_space(1)))
#define AS3 __attribute__((address_space(3)))

// ---------------- Kernel A: L2-normalize + per-row i8 quantize --------------
__global__ __launch_bounds__(256) void knorm(const float* __restrict__ in,
                                             signed char* __restrict__ xq,
                                             float* __restrict__ inv,
                                             float* __restrict__ scl) {
  const int lane = threadIdx.x & 63;
  const int wave = threadIdx.x >> 6;
  const int row = blockIdx.x * 4 + wave;
  const float4* p = (const float4*)(in + (size_t)row * DIM + lane * 8);
  const float4 a = p[0], b = p[1];
  float ss = a.x*a.x + a.y*a.y + a.z*a.z + a.w*a.w
           + b.x*b.x + b.y*b.y + b.z*b.z + b.w*b.w;
  float am = fmaxf(fmaxf(fmaxf(fabsf(a.x), fabsf(a.y)), fmaxf(fabsf(a.z), fabsf(a.w))),
                   fmaxf(fmaxf(fabsf(b.x), fabsf(b.y)), fmaxf(fabsf(b.z), fabsf(b.w))));
  #pragma unroll
  for (int m = 32; m >= 1; m >>= 1) {
    ss += __shfl_xor(ss, m, 64);
    am = fmaxf(am, __shfl_xor(am, m, 64));
  }
  const float iv = 1.0f / fmaxf(sqrtf(ss), 1e-8f);
  const float r127 = 127.0f / am;
  char8 q;
  q[0] = (signed char)(int)rintf(a.x * r127);
  q[1] = (signed char)(int)rintf(a.y * r127);
  q[2] = (signed char)(int)rintf(a.z * r127);
  q[3] = (signed char)(int)rintf(a.w * r127);
  q[4] = (signed char)(int)rintf(b.x * r127);
  q[5] = (signed char)(int)rintf(b.y * r127);
  q[6] = (signed char)(int)rintf(b.z * r127);
  q[7] = (signed char)(int)rintf(b.w * r127);
  *(char8*)(xq + (size_t)row * DIM + lane * 8) = q;
  if (lane == 0) {
    inv[row] = iv;
    scl[row] = am * iv * (1.0f / 127.0f);
  }
}

// ---------------- Kernel B: i8 Gram + fused running argmax (packed keys) ----
// 4 waves x 64 rows; A register-resident (128 VGPR). B tiles (64c x 128k =
// 8 KB) in 4 LDS buffers, depth-3 prefetch via global_load_lds(16B), counted
// vmcnt(4) + ONE s_barrier per K-step (buffer-overwrite protection only).
// B fragments are plain LDS loads software-pipelined one 8-MFMA cluster
// ahead; compiler emits fine-grained lgkmcnt so MFMA starts as reads land.
// No intra-K-step barriers, no manual lgkm waits, no sched_barrier.
__global__ __launch_bounds__(256, 2) void kdots(const signed char* __restrict__ xq,
                                                const float* __restrict__ scl,
                                                uint32_t* __restrict__ keys) {
  const int tid  = threadIdx.x;
  const int lane = tid & 63;
  const int wave = tid >> 6;
  const int bx = blockIdx.x;
  const int cs = bx & (CSPLIT - 1);     // same-cs blocks land on same XCD (%8)
  const int rb = bx >> 3;
  const int rowbase  = rb * BM + wave * 64;
  const int colsplit = cs * COLS_PER_SPLIT;
  // the one tile (per wave) containing diagonal elements, or -1
  const int tdiag = ((rowbase >> 11) == cs) ? ((rowbase - colsplit) >> 6) : -1;

  __shared__ signed char lds[4][NT * BK];   // 4 x 8 KB
  __shared__ float sscl[COLS_PER_SPLIT];    // 8 KB

  // stage this slice's column scales into LDS (read in epilogue only)
  {
    const float4* sp = (const float4*)(scl + colsplit + tid * 8);
    float4* dp = (float4*)(sscl + tid * 8);
    dp[0] = sp[0];
    dp[1] = sp[1];
  }

  // ---- A fragments in registers: 4 rowfrags x 8 kfrags(K=64) = 128 VGPR ----
  i32x4 areg[4][8];
  #pragma unroll
  for (int rf = 0; rf < 4; ++rf) {
    const signed char* ap =
        xq + (size_t)(rowbase + rf * 16 + (lane & 15)) * DIM + ((lane >> 4) * 16);
    #pragma unroll
    for (int kf = 0; kf < 8; ++kf)
      areg[rf][kf] = *(const i32x4*)(ap + kf * 64);
  }

  uint32_t rkey[4][4];
  #pragma unroll
  for (int rf = 0; rf < 4; ++rf)
    #pragma unroll
    for (int r = 0; r < 4; ++r) rkey[rf][r] = 0u;

  // stage one 8 KB buffer: 2 global_load_lds(16B) per thread
  auto STAGE = [&](int buf, int p) {
    const int tt = p >> 2, kb2 = p & 3;
    #pragma unroll
    for (int h = 0; h < 2; ++h) {
      const int u = h * 256 + tid;
      const int col = colsplit + tt * NT + ((u >> 7) << 4) + (u & 15);
      const int koff = kb2 * BK + ((u >> 4) & 7) * 16;
      const signed char* g = xq + (size_t)col * DIM + koff;
      char* l = ((char*)&lds[buf][0]) + u * 16;
      __builtin_amdgcn_global_load_lds((AS1 const void*)g, (AS3 void*)l, 16, 0, 0);
    }
  };

  __syncthreads();   // sscl visible; drains all prior vmem (vmcnt -> 0)
  STAGE(0, 0); STAGE(1, 1); STAGE(2, 2);   // depth-3 prologue: 6 outstanding

#define CLUSTER(Q, BA, BB)                                                     \
  __builtin_amdgcn_s_setprio(1);                                              \
  acc[0][Q] = __builtin_amdgcn_mfma_i32_16x16x64_i8(a0, BA, acc[0][Q], 0,0,0);\
  acc[1][Q] = __builtin_amdgcn_mfma_i32_16x16x64_i8(a1, BA, acc[1][Q], 0,0,0);\
  acc[2][Q] = __builtin_amdgcn_mfma_i32_16x16x64_i8(a2, BA, acc[2][Q], 0,0,0);\
  acc[3][Q] = __builtin_amdgcn_mfma_i32_16x16x64_i8(a3, BA, acc[3][Q], 0,0,0);\
  acc[0][Q] = __builtin_amdgcn_mfma_i32_16x16x64_i8(a4, BB, acc[0][Q], 0,0,0);\
  acc[1][Q] = __builtin_amdgcn_mfma_i32_16x16x64_i8(a5, BB, acc[1][Q], 0,0,0);\
  acc[2][Q] = __builtin_amdgcn_mfma_i32_16x16x64_i8(a6, BB, acc[2][Q], 0,0,0);\
  acc[3][Q] = __builtin_amdgcn_mfma_i32_16x16x64_i8(a7, BB, acc[3][Q], 0,0,0);\
  __builtin_amdgcn_s_setprio(0);

  for (int t = 0; t < NTILES; ++t) {
    i32x4 acc[4][4];
    #pragma unroll
    for (int rf = 0; rf < 4; ++rf)
      #pragma unroll
      for (int cf = 0; cf < 4; ++cf) acc[rf][cf] = (i32x4){0, 0, 0, 0};

    #pragma unroll
    for (int kb = 0; kb < PPT; ++kb) {
      // buffer for this K-step = (t*4+kb)&3 = kb&3 (compile-time per kb)
      asm volatile("s_waitcnt vmcnt(4)" ::: "memory"); // this buf's loads in
      __builtin_amdgcn_s_barrier();                    // ...across ALL waves;
      asm volatile("" ::: "memory");                   // prev buf fully read
      STAGE((kb + 3) & 3, (t * PPT + kb + 3) & (NPHASE - 1)); // depth-3
      const i32x4* bp = (const i32x4*)&lds[kb & 3][0] + lane;
      const i32x4 a0 = areg[0][kb*2],   a1 = areg[1][kb*2];
      const i32x4 a2 = areg[2][kb*2],   a3 = areg[3][kb*2];
      const i32x4 a4 = areg[0][kb*2+1], a5 = areg[1][kb*2+1];
      const i32x4 a6 = areg[2][kb*2+1], a7 = areg[3][kb*2+1];
      i32x4 b0a = bp[0],   b0b = bp[64];    // q0
      i32x4 b1a = bp[128], b1b = bp[192];   // q1 in flight
      CLUSTER(0, b0a, b0b)
      b0a = bp[256]; b0b = bp[320];         // q2 in flight
      CLUSTER(1, b1a, b1b)
      b1a = bp[384]; b1b = bp[448];         // q3 in flight
      CLUSTER(2, b0a, b0b)
      CLUSTER(3, b1a, b1b)
    }

    // ---- fused argmax over this 64-col tile: packed-key running max --------
    const int colb0 = t * NT;
    if (t == tdiag) {
      #pragma unroll
      for (int cf = 0; cf < 4; ++cf) {
        const float sc = sscl[colb0 + cf * 16 + (lane & 15)];
        const uint32_t code = 2047u - (uint32_t)(colb0 + cf * 16 + (lane & 15));
        const int gcol = colsplit + colb0 + cf * 16 + (lane & 15);
        #pragma unroll
        for (int rf = 0; rf < 4; ++rf) {
          #pragma unroll
          for (int r = 0; r < 4; ++r) {
            const int grow = rowbase + rf * 16 + (lane >> 4) * 4 + r;
            const float dv = fmaf((float)acc[rf][cf][r], sc, 4096.0f);
            uint32_t key = (__float_as_uint(dv) & 0xFFFFF800u) | code;
            if (gcol == grow) key = 0u;               // mask diagonal
            rkey[rf][r] = rkey[rf][r] > key ? rkey[rf][r] : key;
          }
        }
      }
    } else {
      #pragma unroll
      for (int cf = 0; cf < 4; ++cf) {
        const float sc = sscl[colb0 + cf * 16 + (lane & 15)];
        const uint32_t code = 2047u - (uint32_t)(colb0 + cf * 16 + (lane & 15));
        #pragma unroll
        for (int rf = 0; rf < 4; ++rf) {
          #pragma unroll
          for (int r = 0; r < 4; ++r) {
            const float dv = fmaf((float)acc[rf][cf][r], sc, 4096.0f);
            const uint32_t key = (__float_as_uint(dv) & 0xFFFFF800u) | code;
            rkey[rf][r] = rkey[rf][r] > key ? rkey[rf][r] : key;
          }
        }
      }
    }
  }
#undef CLUSTER

  // ---- cross-lane key max within each 16-lane group ------------------------
  #pragma unroll
  for (int m = 1; m <= 8; m <<= 1) {
    #pragma unroll
    for (int rf = 0; rf < 4; ++rf) {
      #pragma unroll
      for (int r = 0; r < 4; ++r) {
        const uint32_t ok =
            (uint32_t)__shfl_xor((int)rkey[rf][r], m, 64);
        rkey[rf][r] = rkey[rf][r] > ok ? rkey[rf][r] : ok;
      }
    }
  }
  if ((lane & 15) == 0) {
    #pragma unroll
    for (int rf = 0; rf < 4; ++rf) {
      #pragma unroll
      for (int r = 0; r < 4; ++r) {
        const int grow = rowbase + rf * 16 + (lane >> 4) * 4 + r;
        keys[cs * NROWS + grow] = rkey[rf][r];
      }
    }
  }
}

// ---------------- Kernel C1: combine splits, exact f32 distance + log -------
__global__ __launch_bounds__(256) void kdist(const float* __restrict__ in,
                                             const float* __restrict__ inv,
                                             const uint32_t* __restrict__ keys,
                                             float* __restrict__ partial) {
  __shared__ float acc4[4];
  const int lane = threadIdx.x & 63;
  const int wave = threadIdx.x >> 6;
  const int row = blockIdx.x * 4 + wave;
  uint32_t bk = 0u; int bs = 0;
  #pragma unroll
  for (int s = 0; s < CSPLIT; ++s) {
    const uint32_t k = keys[s * NROWS + row];
    if (k > bk) { bk = k; bs = s; }
  }
  const int bi = bs * COLS_PER_SPLIT + 2047 - (int)(bk & 2047u);
  const float ii = inv[row], jj = inv[bi];
  const float4* pi = (const float4*)(in + (size_t)row * DIM + lane * 8);
  const float4* pj = (const float4*)(in + (size_t)bi * DIM + lane * 8);
  const float4 a0 = pi[0], a1 = pi[1], b0 = pj[0], b1 = pj[1];
  float d, ss = 0.0f;
  d = a0.x*ii - b0.x*jj + 1e-8f; ss += d*d;
  d = a0.y*ii - b0.y*jj + 1e-8f; ss += d*d;
  d = a0.z*ii - b0.z*jj + 1e-8f; ss += d*d;
  d = a0.w*ii - b0.w*jj + 1e-8f; ss += d*d;
  d = a1.x*ii - b1.x*jj + 1e-8f; ss += d*d;
  d = a1.y*ii - b1.y*jj + 1e-8f; ss += d*d;
  d = a1.z*ii - b1.z*jj + 1e-8f; ss += d*d;
  d = a1.w*ii - b1.w*jj + 1e-8f; ss += d*d;
  #pragma unroll
  for (int m = 32; m >= 1; m >>= 1) ss += __shfl_xor(ss, m, 64);
  if (lane == 0) acc4[wave] = logf(sqrtf(ss) + 1e-8f);
  __syncthreads();
  if (threadIdx.x == 0)
    partial[blockIdx.x] = acc4[0] + acc4[1] + acc4[2] + acc4[3];
}

// ---------------- Kernel C2: final reduce -> loss ---------------------------
__global__ __launch_bounds__(256) void kfinal(const float* __restrict__ partial,
                                              float* __restrict__ out) {
  __shared__ float acc4[4];
  const int lane = threadIdx.x & 63;
  const int wave = threadIdx.x >> 6;
  float s = 0.0f;
  for (int i = threadIdx.x; i < NROWS / 4; i += 256) s += partial[i];
  #pragma unroll
  for (int m = 32; m >= 1; m >>= 1) s += __shfl_xor(s, m, 64);
  if (lane == 0) acc4[wave] = s;
  __syncthreads();
  if (threadIdx.x == 0)
    out[0] = -(acc4[0] + acc4[1] + acc4[2] + acc4[3]) * (1.0f / (float)NROWS);
}

extern "C" void kernel_launch(void* const* d_in, const int* in_sizes, int n_in,
                              void* d_out, int out_size, void* d_ws, size_t ws_size,
                              hipStream_t stream) {
  const float* in = (const float*)d_in[0];
  char* ws = (char*)d_ws;
  signed char* xq   = (signed char*)(ws);                  //  8,388,608 B
  float*       inv  = (float*)(ws + 8388608);              //     65,536 B
  float*       scl  = (float*)(ws + 8454144);              //     65,536 B
  uint32_t*    keys = (uint32_t*)(ws + 8519680);           //    524,288 B
  float*       part = (float*)(ws + 9043968);              //     16,384 B

  knorm<<<NROWS / 4, 256, 0, stream>>>(in, xq, inv, scl);
  kdots<<<(NROWS / BM) * CSPLIT, 256, 0, stream>>>(xq, scl, keys);
  kdist<<<NROWS / 4, 256, 0, stream>>>(in, inv, keys, part);
  kfinal<<<1, 256, 0, stream>>>(part, (float*)d_out);
}